// Round 1
// baseline (568.450 us; speedup 1.0000x reference)
//
#include <hip/hip_runtime.h>
#include <hip/hip_bf16.h>

// MultimodalFusion: B*H=16384 tokens, NMOD=4, M=512, NH=8, DH=64, FFN=2048.
// Pipeline: pack(bf16) -> qkv+attn -> outproj+LN1+agg -> ffn1+gelu -> ffn2+LN2.
// All GEMMs: mfma_f32_16x16x32_bf16, fp32 accum, XOR-swizzled LDS staging (BK=64).
//
// ws layout (bytes):
//   wqkv_b  @ 0          1,572,864   (1536x512 bf16)
//   wout_b  @ 1572864      524,288   (512x512)
//   w1_b    @ 2097152    2,097,152   (2048x512)
//   w2_b    @ 4194304    2,097,152   (512x2048)
//   x4      @ 6291456   67,108,864   (65536x512 bf16, row r = token*4+modality)
//   o_buf   @ 73400320  67,108,864   (65536x512 bf16)  [hidden overlays after K2]
//   agg_f   @ 140509184 33,554,432   (16384x512 fp32)
//   agg_b   @ 174063616 16,777,216   (16384x512 bf16)
//   total 190,840,832

typedef __attribute__((ext_vector_type(8))) short s16x8;
typedef __attribute__((ext_vector_type(4))) float f32x4;

__device__ __forceinline__ unsigned short f2bf(float f) {
  unsigned int u = __float_as_uint(f);
  u += 0x7fffu + ((u >> 16) & 1u);
  return (unsigned short)(u >> 16);
}
__device__ __forceinline__ float bf2f(unsigned short s) {
  return __uint_as_float(((unsigned int)s) << 16);
}
__device__ __forceinline__ f32x4 mfma16(s16x8 a, s16x8 b, f32x4 c) {
  return __builtin_amdgcn_mfma_f32_16x16x32_bf16(a, b, c, 0, 0, 0);
}
// byte offset into a [rows][64] bf16 tile (128B rows), XOR-swizzled 16B granules
__device__ __forceinline__ int swz(int row, int bir) {
  return row * 128 + ((((row) & 7) << 4) ^ bir);
}

// ---------------------------------------------------------------- pack
__global__ void pack_kernel(const float* __restrict__ wqkv, const float* __restrict__ wout,
                            const float* __restrict__ w1, const float* __restrict__ w2,
                            const float* __restrict__ x0, const float* __restrict__ x1,
                            const float* __restrict__ x2, const float* __restrict__ x3,
                            unsigned short* __restrict__ o_wqkv, unsigned short* __restrict__ o_wout,
                            unsigned short* __restrict__ o_w1, unsigned short* __restrict__ o_w2,
                            unsigned short* __restrict__ o_x4) {
  const long c0 = 196608, c1 = 262144, c2 = 524288, c3 = 786432, c4 = 9175040;
  for (long v = (long)blockIdx.x * blockDim.x + threadIdx.x; v < c4;
       v += (long)gridDim.x * blockDim.x) {
    const float* src;
    unsigned short* dst;
    if (v < c0) { src = wqkv + v * 4; dst = o_wqkv + v * 4; }
    else if (v < c1) { long u = v - c0; src = wout + u * 4; dst = o_wout + u * 4; }
    else if (v < c2) { long u = v - c1; src = w1 + u * 4; dst = o_w1 + u * 4; }
    else if (v < c3) { long u = v - c2; src = w2 + u * 4; dst = o_w2 + u * 4; }
    else {
      long u = v - c3; long e = u * 4; long r = e >> 9; int i = (int)(e & 511);
      int s = (int)(r & 3); long n = r >> 2;
      const float* xs = (s == 0) ? x0 : (s == 1) ? x1 : (s == 2) ? x2 : x3;
      src = xs + n * 512 + i; dst = o_x4 + e;
    }
    float4 f = *reinterpret_cast<const float4*>(src);
    ushort4 hb;
    hb.x = f2bf(f.x); hb.y = f2bf(f.y); hb.z = f2bf(f.z); hb.w = f2bf(f.w);
    *reinterpret_cast<ushort4*>(dst) = hb;
  }
}

// ---------------------------------------------------------------- K1: qkv + attention
// grid (8 heads, 512 token-blocks of 32 tokens = 128 X-rows), 256 threads.
__launch_bounds__(256)
__global__ void qkv_attn_kernel(const unsigned short* __restrict__ x4,
                                const unsigned short* __restrict__ wqkv,
                                const float* __restrict__ in_b,
                                unsigned short* __restrict__ o_out) {
  const int h = blockIdx.x;
  const int tb = blockIdx.y;
  const int tid = threadIdx.x, lane = tid & 63, w = tid >> 6;
  const int wm = w >> 1, wn = w & 1;

  __shared__ __align__(16) unsigned char smem[51200];
  unsigned short* aT = (unsigned short*)smem;            // [128][64] staging
  unsigned short* bT = (unsigned short*)(smem + 16384);  // [192][64] staging
  unsigned short* qkvT = (unsigned short*)smem;          // [128][192] (overlays staging)
  float* scoresLds = (float*)(smem + 49152);             // [32][16]

  f32x4 acc[4][6];
#pragma unroll
  for (int i = 0; i < 4; ++i)
#pragma unroll
    for (int j = 0; j < 6; ++j) acc[i][j] = (f32x4){0.f, 0.f, 0.f, 0.f};

  const long rowBase = (long)tb * 128;

  for (int kk = 0; kk < 8; ++kk) {
    const int k0 = kk * 64;
#pragma unroll
    for (int it = 0; it < 4; ++it) {  // A: 128 rows x 8 chunks
      int cid = tid + it * 256, lr = cid >> 3, c8 = cid & 7;
      s16x8 v = *(const s16x8*)(x4 + (rowBase + lr) * 512 + k0 + c8 * 8);
      *(s16x8*)((unsigned char*)aT + swz(lr, c8 * 16)) = v;
    }
#pragma unroll
    for (int it = 0; it < 6; ++it) {  // B: 192 cols x 8 chunks
      int cid = tid + it * 256, bc = cid >> 3, c8 = cid & 7;
      int wrow = (bc < 64) ? (h * 64 + bc)
                : (bc < 128) ? (512 + h * 64 + (bc - 64))
                             : (1024 + h * 64 + (bc - 128));
      s16x8 v = *(const s16x8*)(wqkv + (long)wrow * 512 + k0 + c8 * 8);
      *(s16x8*)((unsigned char*)bT + swz(bc, c8 * 16)) = v;
    }
    __syncthreads();
#pragma unroll
    for (int k2 = 0; k2 < 2; ++k2) {
      s16x8 af[4], bfr[6];
      const int bir = k2 * 64 + ((lane >> 4) << 4);
#pragma unroll
      for (int mi = 0; mi < 4; ++mi) {
        int row = wm * 64 + mi * 16 + (lane & 15);
        af[mi] = *(const s16x8*)((unsigned char*)aT + swz(row, bir));
      }
#pragma unroll
      for (int ni = 0; ni < 6; ++ni) {
        int col = wn * 96 + ni * 16 + (lane & 15);
        bfr[ni] = *(const s16x8*)((unsigned char*)bT + swz(col, bir));
      }
#pragma unroll
      for (int mi = 0; mi < 4; ++mi)
#pragma unroll
        for (int ni = 0; ni < 6; ++ni)
          acc[mi][ni] = mfma16(af[mi], bfr[ni], acc[mi][ni]);
    }
    __syncthreads();
  }

  // acc -> qkvT (bf16) with qkv bias.  D layout: col=lane&15, row=(lane>>4)*4+r.
#pragma unroll
  for (int mi = 0; mi < 4; ++mi)
#pragma unroll
    for (int ni = 0; ni < 6; ++ni) {
      int col = wn * 96 + ni * 16 + (lane & 15);
      int wrow = (col < 64) ? (h * 64 + col)
                : (col < 128) ? (512 + h * 64 + (col - 64))
                              : (1024 + h * 64 + (col - 128));
      float bias = in_b[wrow];
      int row0 = wm * 64 + mi * 16 + ((lane >> 4) << 2);
#pragma unroll
      for (int r = 0; r < 4; ++r)
        qkvT[(row0 + r) * 192 + col] = f2bf(acc[mi][ni][r] + bias);
    }
  __syncthreads();

  // attention: 32 tokens, 8 threads each
  const int token = tid >> 3, sub = tid & 7;
  {
    int p0 = sub * 2;
#pragma unroll
    for (int pp = 0; pp < 2; ++pp) {
      int p = p0 + pp, s = p >> 2, t = p & 3;
      const unsigned short* qr = qkvT + (token * 4 + s) * 192;
      const unsigned short* kr = qkvT + (token * 4 + t) * 192 + 64;
      float d = 0.f;
      for (int i = 0; i < 64; ++i) d += bf2f(qr[i]) * bf2f(kr[i]);
      scoresLds[token * 16 + p] = d * 0.125f;
    }
  }
  __syncthreads();
  float attnP[4][4];
#pragma unroll
  for (int s = 0; s < 4; ++s) {
    float m = -1e30f;
#pragma unroll
    for (int t = 0; t < 4; ++t) m = fmaxf(m, scoresLds[token * 16 + s * 4 + t]);
    float sum = 0.f;
#pragma unroll
    for (int t = 0; t < 4; ++t) {
      float e = expf(scoresLds[token * 16 + s * 4 + t] - m);
      attnP[s][t] = e; sum += e;
    }
    float inv = 1.f / sum;
#pragma unroll
    for (int t = 0; t < 4; ++t) attnP[s][t] *= inv;
  }
  float vv[4][8];
#pragma unroll
  for (int t = 0; t < 4; ++t)
#pragma unroll
    for (int d = 0; d < 8; ++d)
      vv[t][d] = bf2f(qkvT[(token * 4 + t) * 192 + 128 + sub * 8 + d]);
#pragma unroll
  for (int s = 0; s < 4; ++s) {
    long orow = rowBase + token * 4 + s;
    unsigned short* dst = o_out + orow * 512 + h * 64 + sub * 8;
    s16x8 ov;
#pragma unroll
    for (int d = 0; d < 8; ++d) {
      float o = 0.f;
#pragma unroll
      for (int t = 0; t < 4; ++t) o += attnP[s][t] * vv[t][d];
      ov[d] = (short)f2bf(o);
    }
    *(s16x8*)dst = ov;
  }
}

// ---------------------------------------------------------------- K2: out_proj + LN1 + agg
// grid 2048 (8 tokens = 32 X-rows each), 256 threads.
__launch_bounds__(256)
__global__ void outproj_ln1_kernel(const unsigned short* __restrict__ o_in,
                                   const unsigned short* __restrict__ wout,
                                   const float* __restrict__ out_b,
                                   const float* __restrict__ x0, const float* __restrict__ x1,
                                   const float* __restrict__ x2, const float* __restrict__ x3,
                                   const float* __restrict__ ln1_g, const float* __restrict__ ln1_b,
                                   float* __restrict__ agg_f, unsigned short* __restrict__ agg_b) {
  const int tb = blockIdx.x;
  const int tid = threadIdx.x, lane = tid & 63, w = tid >> 6;
  __shared__ __align__(16) unsigned char smem[53504];
  unsigned short* vt = (unsigned short*)smem;            // [32][512] bf16
  unsigned short* aT = (unsigned short*)(smem + 32768);  // [32][64]
  unsigned short* bT = (unsigned short*)(smem + 36864);  // [128][64]
  float* stats = (float*)(smem + 53248);                 // [32][2]
  const long rowBase = (long)tb * 32;
  const float* xs[4] = {x0, x1, x2, x3};

  for (int ns = 0; ns < 4; ++ns) {
    f32x4 acc[2][2];
#pragma unroll
    for (int i = 0; i < 2; ++i)
#pragma unroll
      for (int j = 0; j < 2; ++j) acc[i][j] = (f32x4){0.f, 0.f, 0.f, 0.f};
    for (int kk = 0; kk < 8; ++kk) {
      const int k0 = kk * 64;
      {
        int lr = tid >> 3, c8 = tid & 7;
        s16x8 v = *(const s16x8*)(o_in + (rowBase + lr) * 512 + k0 + c8 * 8);
        *(s16x8*)((unsigned char*)aT + swz(lr, c8 * 16)) = v;
      }
#pragma unroll
      for (int it = 0; it < 4; ++it) {
        int cid = tid + it * 256, bc = cid >> 3, c8 = cid & 7;
        s16x8 v = *(const s16x8*)(wout + (long)(ns * 128 + bc) * 512 + k0 + c8 * 8);
        *(s16x8*)((unsigned char*)bT + swz(bc, c8 * 16)) = v;
      }
      __syncthreads();
#pragma unroll
      for (int k2 = 0; k2 < 2; ++k2) {
        s16x8 af[2], bfr[2];
        const int bir = k2 * 64 + ((lane >> 4) << 4);
#pragma unroll
        for (int mi = 0; mi < 2; ++mi) {
          int row = mi * 16 + (lane & 15);
          af[mi] = *(const s16x8*)((unsigned char*)aT + swz(row, bir));
        }
#pragma unroll
        for (int ni = 0; ni < 2; ++ni) {
          int col = w * 32 + ni * 16 + (lane & 15);
          bfr[ni] = *(const s16x8*)((unsigned char*)bT + swz(col, bir));
        }
#pragma unroll
        for (int mi = 0; mi < 2; ++mi)
#pragma unroll
          for (int ni = 0; ni < 2; ++ni)
            acc[mi][ni] = mfma16(af[mi], bfr[ni], acc[mi][ni]);
      }
      __syncthreads();
    }
#pragma unroll
    for (int mi = 0; mi < 2; ++mi)
#pragma unroll
      for (int ni = 0; ni < 2; ++ni) {
        int gcol = ns * 128 + w * 32 + ni * 16 + (lane & 15);
        float bias = out_b[gcol];
        int row0 = mi * 16 + ((lane >> 4) << 2);
#pragma unroll
        for (int r = 0; r < 4; ++r)
          vt[(row0 + r) * 512 + gcol] = f2bf(acc[mi][ni][r] + bias);
      }
  }
  __syncthreads();
  {  // per-row LN1 stats (v = attn_out + F)
    int r = tid >> 3, u = tid & 7;
    long gr = rowBase + r; long n = gr >> 2; int s = (int)(gr & 3);
    const float* F = xs[s] + n * 512;
    float sum = 0.f, sq = 0.f;
    for (int j = 0; j < 64; ++j) {
      int c = u + 8 * j;
      float v = bf2f(vt[r * 512 + c]) + F[c];
      sum += v; sq += v * v;
    }
    sum += __shfl_xor(sum, 1); sq += __shfl_xor(sq, 1);
    sum += __shfl_xor(sum, 2); sq += __shfl_xor(sq, 2);
    sum += __shfl_xor(sum, 4); sq += __shfl_xor(sq, 4);
    if (u == 0) {
      float mu = sum * (1.f / 512.f);
      float var = sq * (1.f / 512.f) - mu * mu;
      stats[r * 2] = mu;
      stats[r * 2 + 1] = rsqrtf(var + 1e-5f);
    }
  }
  __syncthreads();
  for (int it = 0; it < 16; ++it) {  // agg over modalities
    int wi = tid + it * 256;
    int tok = wi >> 9, c = wi & 511;
    long gtok = (long)tb * 8 + tok;
    float a = 0.f;
#pragma unroll
    for (int s = 0; s < 4; ++s) {
      int r = tok * 4 + s;
      float v = bf2f(vt[r * 512 + c]) + xs[s][gtok * 512 + c];
      a += (v - stats[r * 2]) * stats[r * 2 + 1];
    }
    float outv = ln1_g[c] * a + 4.f * ln1_b[c];
    agg_f[gtok * 512 + c] = outv;
    agg_b[gtok * 512 + c] = f2bf(outv);
  }
}

// ---------------------------------------------------------------- K3: ffn1 + gelu
// grid (16 N-tiles, 128 M-tiles), 128x128 tile, 256 threads.
__launch_bounds__(256)
__global__ void ffn1_kernel(const unsigned short* __restrict__ aggb,
                            const unsigned short* __restrict__ w1b,
                            const float* __restrict__ b1,
                            unsigned short* __restrict__ hidden) {
  const int bx = blockIdx.x, by = blockIdx.y;
  const int tid = threadIdx.x, lane = tid & 63, w = tid >> 6;
  const int wm = w >> 1, wn = w & 1;
  __shared__ __align__(16) unsigned char smem[32768];
  unsigned short* aT = (unsigned short*)smem;            // [128][64]
  unsigned short* bT = (unsigned short*)(smem + 16384);  // [128][64]
  f32x4 acc[4][4];
#pragma unroll
  for (int i = 0; i < 4; ++i)
#pragma unroll
    for (int j = 0; j < 4; ++j) acc[i][j] = (f32x4){0.f, 0.f, 0.f, 0.f};
  const long rowBase = (long)by * 128;
  const long colBase = (long)bx * 128;
  for (int kk = 0; kk < 8; ++kk) {
    const int k0 = kk * 64;
#pragma unroll
    for (int it = 0; it < 4; ++it) {
      int cid = tid + it * 256, lr = cid >> 3, c8 = cid & 7;
      s16x8 v = *(const s16x8*)(aggb + (rowBase + lr) * 512 + k0 + c8 * 8);
      *(s16x8*)((unsigned char*)aT + swz(lr, c8 * 16)) = v;
    }
#pragma unroll
    for (int it = 0; it < 4; ++it) {
      int cid = tid + it * 256, bc = cid >> 3, c8 = cid & 7;
      s16x8 v = *(const s16x8*)(w1b + (colBase + bc) * 512 + k0 + c8 * 8);
      *(s16x8*)((unsigned char*)bT + swz(bc, c8 * 16)) = v;
    }
    __syncthreads();
#pragma unroll
    for (int k2 = 0; k2 < 2; ++k2) {
      s16x8 af[4], bfr[4];
      const int bir = k2 * 64 + ((lane >> 4) << 4);
#pragma unroll
      for (int mi = 0; mi < 4; ++mi) {
        int row = wm * 64 + mi * 16 + (lane & 15);
        af[mi] = *(const s16x8*)((unsigned char*)aT + swz(row, bir));
      }
#pragma unroll
      for (int ni = 0; ni < 4; ++ni) {
        int col = wn * 64 + ni * 16 + (lane & 15);
        bfr[ni] = *(const s16x8*)((unsigned char*)bT + swz(col, bir));
      }
#pragma unroll
      for (int mi = 0; mi < 4; ++mi)
#pragma unroll
        for (int ni = 0; ni < 4; ++ni)
          acc[mi][ni] = mfma16(af[mi], bfr[ni], acc[mi][ni]);
    }
    __syncthreads();
  }
#pragma unroll
  for (int mi = 0; mi < 4; ++mi)
#pragma unroll
    for (int ni = 0; ni < 4; ++ni) {
      long gcol = colBase + wn * 64 + ni * 16 + (lane & 15);
      float bias = b1[gcol];
      int row0 = wm * 64 + mi * 16 + ((lane >> 4) << 2);
#pragma unroll
      for (int r = 0; r < 4; ++r) {
        float x = acc[mi][ni][r] + bias;
        float g = 0.5f * x * (1.f + erff(x * 0.70710678118f));
        hidden[(rowBase + row0 + r) * 2048 + gcol] = f2bf(g);
      }
    }
}

// ---------------------------------------------------------------- K4: ffn2 + LN2
// grid 512 (32 tokens each), 256 threads.
__launch_bounds__(256)
__global__ void ffn2_ln2_kernel(const unsigned short* __restrict__ hidden,
                                const unsigned short* __restrict__ w2b,
                                const float* __restrict__ b2,
                                const float* __restrict__ agg_f,
                                const float* __restrict__ ln2_g,
                                const float* __restrict__ ln2_b,
                                float* __restrict__ out) {
  const int tb = blockIdx.x;
  const int tid = threadIdx.x, lane = tid & 63, w = tid >> 6;
  __shared__ __align__(16) unsigned char smem[53504];
  unsigned short* vt = (unsigned short*)smem;            // [32][512]
  unsigned short* aT = (unsigned short*)(smem + 32768);  // [32][64]
  unsigned short* bT = (unsigned short*)(smem + 36864);  // [128][64]
  float* stats = (float*)(smem + 53248);
  const long rowBase = (long)tb * 32;  // token rows

  for (int ns = 0; ns < 4; ++ns) {
    f32x4 acc[2][2];
#pragma unroll
    for (int i = 0; i < 2; ++i)
#pragma unroll
      for (int j = 0; j < 2; ++j) acc[i][j] = (f32x4){0.f, 0.f, 0.f, 0.f};
    for (int kk = 0; kk < 32; ++kk) {
      const int k0 = kk * 64;
      {
        int lr = tid >> 3, c8 = tid & 7;
        s16x8 v = *(const s16x8*)(hidden + (rowBase + lr) * 2048 + k0 + c8 * 8);
        *(s16x8*)((unsigned char*)aT + swz(lr, c8 * 16)) = v;
      }
#pragma unroll
      for (int it = 0; it < 4; ++it) {
        int cid = tid + it * 256, bc = cid >> 3, c8 = cid & 7;
        s16x8 v = *(const s16x8*)(w2b + (long)(ns * 128 + bc) * 2048 + k0 + c8 * 8);
        *(s16x8*)((unsigned char*)bT + swz(bc, c8 * 16)) = v;
      }
      __syncthreads();
#pragma unroll
      for (int k2 = 0; k2 < 2; ++k2) {
        s16x8 af[2], bfr[2];
        const int bir = k2 * 64 + ((lane >> 4) << 4);
#pragma unroll
        for (int mi = 0; mi < 2; ++mi) {
          int row = mi * 16 + (lane & 15);
          af[mi] = *(const s16x8*)((unsigned char*)aT + swz(row, bir));
        }
#pragma unroll
        for (int ni = 0; ni < 2; ++ni) {
          int col = w * 32 + ni * 16 + (lane & 15);
          bfr[ni] = *(const s16x8*)((unsigned char*)bT + swz(col, bir));
        }
#pragma unroll
        for (int mi = 0; mi < 2; ++mi)
#pragma unroll
          for (int ni = 0; ni < 2; ++ni)
            acc[mi][ni] = mfma16(af[mi], bfr[ni], acc[mi][ni]);
      }
      __syncthreads();
    }
#pragma unroll
    for (int mi = 0; mi < 2; ++mi)
#pragma unroll
      for (int ni = 0; ni < 2; ++ni) {
        int gcol = ns * 128 + w * 32 + ni * 16 + (lane & 15);
        float bias = b2[gcol];
        int row0 = mi * 16 + ((lane >> 4) << 2);
#pragma unroll
        for (int r = 0; r < 4; ++r)
          vt[(row0 + r) * 512 + gcol] = f2bf(acc[mi][ni][r] + bias);
      }
  }
  __syncthreads();
  {
    int r = tid >> 3, u = tid & 7;
    const float* ag = agg_f + (rowBase + r) * 512;
    float sum = 0.f, sq = 0.f;
    for (int j = 0; j < 64; ++j) {
      int c = u + 8 * j;
      float v = bf2f(vt[r * 512 + c]) + ag[c];
      sum += v; sq += v * v;
    }
    sum += __shfl_xor(sum, 1); sq += __shfl_xor(sq, 1);
    sum += __shfl_xor(sum, 2); sq += __shfl_xor(sq, 2);
    sum += __shfl_xor(sum, 4); sq += __shfl_xor(sq, 4);
    if (u == 0) {
      float mu = sum * (1.f / 512.f);
      float var = sq * (1.f / 512.f) - mu * mu;
      stats[r * 2] = mu;
      stats[r * 2 + 1] = rsqrtf(var + 1e-5f);
    }
  }
  __syncthreads();
  for (int it = 0; it < 64; ++it) {
    int wi = tid + it * 256;
    int r = wi >> 9, c = wi & 511;
    float v = bf2f(vt[r * 512 + c]) + agg_f[(rowBase + r) * 512 + c];
    out[(rowBase + r) * 512 + c] =
        (v - stats[r * 2]) * stats[r * 2 + 1] * ln2_g[c] + ln2_b[c];
  }
}

// ---------------------------------------------------------------- launch
extern "C" void kernel_launch(void* const* d_in, const int* in_sizes, int n_in,
                              void* d_out, int out_size, void* d_ws, size_t ws_size,
                              hipStream_t stream) {
  (void)in_sizes; (void)n_in; (void)out_size;
  const float* x0 = (const float*)d_in[0];
  const float* x1 = (const float*)d_in[1];
  const float* x2 = (const float*)d_in[2];
  const float* x3 = (const float*)d_in[3];
  const float* in_w = (const float*)d_in[4];
  const float* in_b = (const float*)d_in[5];
  const float* out_w = (const float*)d_in[6];
  const float* out_b = (const float*)d_in[7];
  const float* ln1_g = (const float*)d_in[8];
  const float* ln1_b = (const float*)d_in[9];
  const float* w1 = (const float*)d_in[10];
  const float* b1 = (const float*)d_in[11];
  const float* w2 = (const float*)d_in[12];
  const float* b2 = (const float*)d_in[13];
  const float* ln2_g = (const float*)d_in[14];
  const float* ln2_b = (const float*)d_in[15];
  float* out = (float*)d_out;

  unsigned char* ws = (unsigned char*)d_ws;
  if (ws_size < 190840832u) return;
  unsigned short* wqkv_b = (unsigned short*)(ws + 0);
  unsigned short* wout_b = (unsigned short*)(ws + 1572864);
  unsigned short* w1_b = (unsigned short*)(ws + 2097152);
  unsigned short* w2_b = (unsigned short*)(ws + 4194304);
  unsigned short* x4 = (unsigned short*)(ws + 6291456);
  unsigned short* o_buf = (unsigned short*)(ws + 73400320);
  float* agg_f = (float*)(ws + 140509184);
  unsigned short* agg_b = (unsigned short*)(ws + 174063616);
  unsigned short* hidden = o_buf;  // overlay: o dead after K2

  pack_kernel<<<2048, 256, 0, stream>>>(in_w, out_w, w1, w2, x0, x1, x2, x3,
                                        wqkv_b, wout_b, w1_b, w2_b, x4);
  qkv_attn_kernel<<<dim3(8, 512), 256, 0, stream>>>(x4, wqkv_b, in_b, o_buf);
  outproj_ln1_kernel<<<2048, 256, 0, stream>>>(o_buf, wout_b, out_b, x0, x1, x2, x3,
                                               ln1_g, ln1_b, agg_f, agg_b);
  ffn1_kernel<<<dim3(16, 128), 256, 0, stream>>>(agg_b, w1_b, b1, hidden);
  ffn2_ln2_kernel<<<512, 256, 0, stream>>>(hidden, w2_b, b2, agg_f, ln2_g, ln2_b, out);
}

// Round 2
// 490.507 us; speedup vs baseline: 1.1589x; 1.1589x over previous
//
#include <hip/hip_runtime.h>
#include <hip/hip_bf16.h>

// MultimodalFusion: B*H=16384 tokens, NMOD=4, M=512, NH=8, DH=64, FFN=2048.
// R2: XCD-locality swizzle for qkv_attn + ffn1; padded/vectorized attention
// phase; vt XOR-swizzle + residual folded at epilogue in K2/K4.
//
// ws layout (bytes):
//   wqkv_b  @ 0          1,572,864   (1536x512 bf16)
//   wout_b  @ 1572864      524,288   (512x512)
//   w1_b    @ 2097152    2,097,152   (2048x512)
//   w2_b    @ 4194304    2,097,152   (512x2048)
//   x4      @ 6291456   67,108,864   (65536x512 bf16, row r = token*4+modality)
//   o_buf   @ 73400320  67,108,864   (65536x512 bf16)  [hidden overlays after K2]
//   agg_f   @ 140509184 33,554,432   (16384x512 fp32)
//   agg_b   @ 174063616 16,777,216   (16384x512 bf16)
//   total 190,840,832

typedef __attribute__((ext_vector_type(8))) short s16x8;
typedef __attribute__((ext_vector_type(4))) float f32x4;

__device__ __forceinline__ unsigned short f2bf(float f) {
  unsigned int u = __float_as_uint(f);
  u += 0x7fffu + ((u >> 16) & 1u);
  return (unsigned short)(u >> 16);
}
__device__ __forceinline__ float bf2f(unsigned short s) {
  return __uint_as_float(((unsigned int)s) << 16);
}
__device__ __forceinline__ f32x4 mfma16(s16x8 a, s16x8 b, f32x4 c) {
  return __builtin_amdgcn_mfma_f32_16x16x32_bf16(a, b, c, 0, 0, 0);
}
// byte offset into a [rows][64] bf16 staging tile (128B rows), XOR-swizzled
__device__ __forceinline__ int swz(int row, int bir) {
  return row * 128 + ((((row) & 7) << 4) ^ bir);
}
// byte offset into a [rows][512] bf16 vt tile (1024B rows), XOR-swizzled 16B granules
__device__ __forceinline__ int vtoff(int r, int c) {
  return r * 1024 + ((c * 2) ^ ((r & 7) << 4));
}

// ---------------------------------------------------------------- pack
__global__ void pack_kernel(const float* __restrict__ wqkv, const float* __restrict__ wout,
                            const float* __restrict__ w1, const float* __restrict__ w2,
                            const float* __restrict__ x0, const float* __restrict__ x1,
                            const float* __restrict__ x2, const float* __restrict__ x3,
                            unsigned short* __restrict__ o_wqkv, unsigned short* __restrict__ o_wout,
                            unsigned short* __restrict__ o_w1, unsigned short* __restrict__ o_w2,
                            unsigned short* __restrict__ o_x4) {
  const long c0 = 196608, c1 = 262144, c2 = 524288, c3 = 786432, c4 = 9175040;
  for (long v = (long)blockIdx.x * blockDim.x + threadIdx.x; v < c4;
       v += (long)gridDim.x * blockDim.x) {
    const float* src;
    unsigned short* dst;
    if (v < c0) { src = wqkv + v * 4; dst = o_wqkv + v * 4; }
    else if (v < c1) { long u = v - c0; src = wout + u * 4; dst = o_wout + u * 4; }
    else if (v < c2) { long u = v - c1; src = w1 + u * 4; dst = o_w1 + u * 4; }
    else if (v < c3) { long u = v - c2; src = w2 + u * 4; dst = o_w2 + u * 4; }
    else {
      long u = v - c3; long e = u * 4; long r = e >> 9; int i = (int)(e & 511);
      int s = (int)(r & 3); long n = r >> 2;
      const float* xs = (s == 0) ? x0 : (s == 1) ? x1 : (s == 2) ? x2 : x3;
      src = xs + n * 512 + i; dst = o_x4 + e;
    }
    float4 f = *reinterpret_cast<const float4*>(src);
    ushort4 hb;
    hb.x = f2bf(f.x); hb.y = f2bf(f.y); hb.z = f2bf(f.z); hb.w = f2bf(f.w);
    *reinterpret_cast<ushort4*>(dst) = hb;
  }
}

// ---------------------------------------------------------------- K1: qkv + attention
// flat grid 4096; bijective swizzle: the 8 head-blocks of one token-block get
// wgids == same (mod 8) -> same XCD, adjacent per-XCD slots -> x4 tile L2-hits.
__launch_bounds__(256)
__global__ void qkv_attn_kernel(const unsigned short* __restrict__ x4,
                                const unsigned short* __restrict__ wqkv,
                                const float* __restrict__ in_b,
                                unsigned short* __restrict__ o_out) {
  const int wg = blockIdx.x;
  const int slot = wg >> 3, xcd = wg & 7;
  const int tb = ((slot >> 3) << 3) | xcd;  // [0,512)
  const int h = slot & 7;                   // [0,8)
  const int tid = threadIdx.x, lane = tid & 63, w = tid >> 6;
  const int wm = w >> 1, wn = w & 1;
  const int QS = 200;  // qkvT row stride (u16): 400B == 4 mod 32 dwords

  __shared__ __align__(16) unsigned char smem[53248];
  unsigned short* aT = (unsigned short*)smem;            // [128][64] staging
  unsigned short* bT = (unsigned short*)(smem + 16384);  // [192][64] staging
  unsigned short* qkvT = (unsigned short*)smem;          // [128][QS] (overlays staging)
  float* scoresLds = (float*)(smem + 51200);             // [32][16]

  f32x4 acc[4][6];
#pragma unroll
  for (int i = 0; i < 4; ++i)
#pragma unroll
    for (int j = 0; j < 6; ++j) acc[i][j] = (f32x4){0.f, 0.f, 0.f, 0.f};

  const long rowBase = (long)tb * 128;

  for (int kk = 0; kk < 8; ++kk) {
    const int k0 = kk * 64;
#pragma unroll
    for (int it = 0; it < 4; ++it) {  // A: 128 rows x 8 chunks
      int cid = tid + it * 256, lr = cid >> 3, c8 = cid & 7;
      s16x8 v = *(const s16x8*)(x4 + (rowBase + lr) * 512 + k0 + c8 * 8);
      *(s16x8*)((unsigned char*)aT + swz(lr, c8 * 16)) = v;
    }
#pragma unroll
    for (int it = 0; it < 6; ++it) {  // B: 192 cols x 8 chunks
      int cid = tid + it * 256, bc = cid >> 3, c8 = cid & 7;
      int wrow = (bc < 64) ? (h * 64 + bc)
                : (bc < 128) ? (512 + h * 64 + (bc - 64))
                             : (1024 + h * 64 + (bc - 128));
      s16x8 v = *(const s16x8*)(wqkv + (long)wrow * 512 + k0 + c8 * 8);
      *(s16x8*)((unsigned char*)bT + swz(bc, c8 * 16)) = v;
    }
    __syncthreads();
#pragma unroll
    for (int k2 = 0; k2 < 2; ++k2) {
      s16x8 af[4], bfr[6];
      const int bir = k2 * 64 + ((lane >> 4) << 4);
#pragma unroll
      for (int mi = 0; mi < 4; ++mi) {
        int row = wm * 64 + mi * 16 + (lane & 15);
        af[mi] = *(const s16x8*)((unsigned char*)aT + swz(row, bir));
      }
#pragma unroll
      for (int ni = 0; ni < 6; ++ni) {
        int col = wn * 96 + ni * 16 + (lane & 15);
        bfr[ni] = *(const s16x8*)((unsigned char*)bT + swz(col, bir));
      }
#pragma unroll
      for (int mi = 0; mi < 4; ++mi)
#pragma unroll
        for (int ni = 0; ni < 6; ++ni)
          acc[mi][ni] = mfma16(af[mi], bfr[ni], acc[mi][ni]);
    }
    __syncthreads();
  }

  // acc -> qkvT (bf16) with qkv bias.  D layout: col=lane&15, row=(lane>>4)*4+r.
#pragma unroll
  for (int mi = 0; mi < 4; ++mi)
#pragma unroll
    for (int ni = 0; ni < 6; ++ni) {
      int col = wn * 96 + ni * 16 + (lane & 15);
      int wrow = (col < 64) ? (h * 64 + col)
                : (col < 128) ? (512 + h * 64 + (col - 64))
                              : (1024 + h * 64 + (col - 128));
      float bias = in_b[wrow];
      int row0 = wm * 64 + mi * 16 + ((lane >> 4) << 2);
#pragma unroll
      for (int r = 0; r < 4; ++r)
        qkvT[(row0 + r) * QS + col] = f2bf(acc[mi][ni][r] + bias);
    }
  __syncthreads();

  // attention: 32 tokens, 8 threads each; vectorized s16x8 LDS reads
  const int token = tid >> 3, sub = tid & 7;
  {
    int p0 = sub * 2;
#pragma unroll
    for (int pp = 0; pp < 2; ++pp) {
      int p = p0 + pp, s = p >> 2, t = p & 3;
      const unsigned short* qr = qkvT + (token * 4 + s) * QS;
      const unsigned short* kr = qkvT + (token * 4 + t) * QS + 64;
      float d = 0.f;
#pragma unroll
      for (int c = 0; c < 8; ++c) {
        s16x8 qv = *(const s16x8*)(qr + c * 8);
        s16x8 kv = *(const s16x8*)(kr + c * 8);
#pragma unroll
        for (int i = 0; i < 8; ++i)
          d += bf2f((unsigned short)qv[i]) * bf2f((unsigned short)kv[i]);
      }
      scoresLds[token * 16 + p] = d * 0.125f;
    }
  }
  __syncthreads();
  float attnP[4][4];
#pragma unroll
  for (int s = 0; s < 4; ++s) {
    float m = -1e30f;
#pragma unroll
    for (int t = 0; t < 4; ++t) m = fmaxf(m, scoresLds[token * 16 + s * 4 + t]);
    float sum = 0.f;
#pragma unroll
    for (int t = 0; t < 4; ++t) {
      float e = expf(scoresLds[token * 16 + s * 4 + t] - m);
      attnP[s][t] = e; sum += e;
    }
    float inv = 1.f / sum;
#pragma unroll
    for (int t = 0; t < 4; ++t) attnP[s][t] *= inv;
  }
  float vv[4][8];
#pragma unroll
  for (int t = 0; t < 4; ++t) {
    s16x8 vvec = *(const s16x8*)(qkvT + (token * 4 + t) * QS + 128 + sub * 8);
#pragma unroll
    for (int d = 0; d < 8; ++d) vv[t][d] = bf2f((unsigned short)vvec[d]);
  }
#pragma unroll
  for (int s = 0; s < 4; ++s) {
    long orow = rowBase + token * 4 + s;
    unsigned short* dst = o_out + orow * 512 + h * 64 + sub * 8;
    s16x8 ov;
#pragma unroll
    for (int d = 0; d < 8; ++d) {
      float o = 0.f;
#pragma unroll
      for (int t = 0; t < 4; ++t) o += attnP[s][t] * vv[t][d];
      ov[d] = (short)f2bf(o);
    }
    *(s16x8*)dst = ov;
  }
}

// ---------------------------------------------------------------- K2: out_proj + LN1 + agg
// grid 2048 (8 tokens = 32 X-rows each), 256 threads. Residual F folded into vt.
__launch_bounds__(256)
__global__ void outproj_ln1_kernel(const unsigned short* __restrict__ o_in,
                                   const unsigned short* __restrict__ wout,
                                   const float* __restrict__ out_b,
                                   const float* __restrict__ x0, const float* __restrict__ x1,
                                   const float* __restrict__ x2, const float* __restrict__ x3,
                                   const float* __restrict__ ln1_g, const float* __restrict__ ln1_b,
                                   float* __restrict__ agg_f, unsigned short* __restrict__ agg_b) {
  const int tb = blockIdx.x;
  const int tid = threadIdx.x, lane = tid & 63, w = tid >> 6;
  __shared__ __align__(16) unsigned char smem[53504];
  unsigned short* vt = (unsigned short*)smem;            // [32][512] bf16, XOR-swizzled
  unsigned short* aT = (unsigned short*)(smem + 32768);  // [32][64]
  unsigned short* bT = (unsigned short*)(smem + 36864);  // [128][64]
  float* stats = (float*)(smem + 53248);                 // [32][2]
  const long rowBase = (long)tb * 32;
  const float* xs[4] = {x0, x1, x2, x3};

  for (int ns = 0; ns < 4; ++ns) {
    f32x4 acc[2][2];
#pragma unroll
    for (int i = 0; i < 2; ++i)
#pragma unroll
      for (int j = 0; j < 2; ++j) acc[i][j] = (f32x4){0.f, 0.f, 0.f, 0.f};
    for (int kk = 0; kk < 8; ++kk) {
      const int k0 = kk * 64;
      {
        int lr = tid >> 3, c8 = tid & 7;
        s16x8 v = *(const s16x8*)(o_in + (rowBase + lr) * 512 + k0 + c8 * 8);
        *(s16x8*)((unsigned char*)aT + swz(lr, c8 * 16)) = v;
      }
#pragma unroll
      for (int it = 0; it < 4; ++it) {
        int cid = tid + it * 256, bc = cid >> 3, c8 = cid & 7;
        s16x8 v = *(const s16x8*)(wout + (long)(ns * 128 + bc) * 512 + k0 + c8 * 8);
        *(s16x8*)((unsigned char*)bT + swz(bc, c8 * 16)) = v;
      }
      __syncthreads();
#pragma unroll
      for (int k2 = 0; k2 < 2; ++k2) {
        s16x8 af[2], bfr[2];
        const int bir = k2 * 64 + ((lane >> 4) << 4);
#pragma unroll
        for (int mi = 0; mi < 2; ++mi) {
          int row = mi * 16 + (lane & 15);
          af[mi] = *(const s16x8*)((unsigned char*)aT + swz(row, bir));
        }
#pragma unroll
        for (int ni = 0; ni < 2; ++ni) {
          int col = w * 32 + ni * 16 + (lane & 15);
          bfr[ni] = *(const s16x8*)((unsigned char*)bT + swz(col, bir));
        }
#pragma unroll
        for (int mi = 0; mi < 2; ++mi)
#pragma unroll
          for (int ni = 0; ni < 2; ++ni)
            acc[mi][ni] = mfma16(af[mi], bfr[ni], acc[mi][ni]);
      }
      __syncthreads();
    }
#pragma unroll
    for (int mi = 0; mi < 2; ++mi)
#pragma unroll
      for (int ni = 0; ni < 2; ++ni) {
        int gcol = ns * 128 + w * 32 + ni * 16 + (lane & 15);
        float bias = out_b[gcol];
        int row0 = mi * 16 + ((lane >> 4) << 2);
#pragma unroll
        for (int r = 0; r < 4; ++r) {
          int rr = row0 + r;
          long grow = rowBase + rr;
          int s = (int)(grow & 3); long n = grow >> 2;
          float F = xs[s][n * 512 + gcol];
          *(unsigned short*)((unsigned char*)vt + vtoff(rr, gcol)) =
              f2bf(acc[mi][ni][r] + bias + F);
        }
      }
  }
  __syncthreads();
  {  // per-row LN1 stats: one wave per 8 rows, full-wave vector reduce
    int wv = tid >> 6, ln = tid & 63;
    for (int i = 0; i < 8; ++i) {
      int r = wv * 8 + i;
      s16x8 v8 = *(const s16x8*)((unsigned char*)vt + vtoff(r, ln * 8));
      float sum = 0.f, sq = 0.f;
#pragma unroll
      for (int d = 0; d < 8; ++d) {
        float v = bf2f((unsigned short)v8[d]);
        sum += v; sq += v * v;
      }
#pragma unroll
      for (int off = 1; off < 64; off <<= 1) {
        sum += __shfl_xor(sum, off); sq += __shfl_xor(sq, off);
      }
      if (ln == 0) {
        float mu = sum * (1.f / 512.f);
        float var = sq * (1.f / 512.f) - mu * mu;
        stats[r * 2] = mu;
        stats[r * 2 + 1] = rsqrtf(var + 1e-5f);
      }
    }
  }
  __syncthreads();
  for (int it = 0; it < 2; ++it) {  // agg over modalities, 8-col chunks
    int ci = tid + it * 256;
    int tok = ci >> 6, c0 = (ci & 63) * 8;
    long gtok = (long)tb * 8 + tok;
    float a[8] = {0.f, 0.f, 0.f, 0.f, 0.f, 0.f, 0.f, 0.f};
#pragma unroll
    for (int s = 0; s < 4; ++s) {
      int r = tok * 4 + s;
      s16x8 v8 = *(const s16x8*)((unsigned char*)vt + vtoff(r, c0));
      float mu = stats[r * 2], is = stats[r * 2 + 1];
#pragma unroll
      for (int d = 0; d < 8; ++d) a[d] += (bf2f((unsigned short)v8[d]) - mu) * is;
    }
    float4 g0 = *(const float4*)(ln1_g + c0);
    float4 g1 = *(const float4*)(ln1_g + c0 + 4);
    float4 b0 = *(const float4*)(ln1_b + c0);
    float4 b1 = *(const float4*)(ln1_b + c0 + 4);
    float ov[8];
    ov[0] = g0.x * a[0] + 4.f * b0.x; ov[1] = g0.y * a[1] + 4.f * b0.y;
    ov[2] = g0.z * a[2] + 4.f * b0.z; ov[3] = g0.w * a[3] + 4.f * b0.w;
    ov[4] = g1.x * a[4] + 4.f * b1.x; ov[5] = g1.y * a[5] + 4.f * b1.y;
    ov[6] = g1.z * a[6] + 4.f * b1.z; ov[7] = g1.w * a[7] + 4.f * b1.w;
    *(float4*)(agg_f + gtok * 512 + c0) = (float4){ov[0], ov[1], ov[2], ov[3]};
    *(float4*)(agg_f + gtok * 512 + c0 + 4) = (float4){ov[4], ov[5], ov[6], ov[7]};
    s16x8 ab;
#pragma unroll
    for (int d = 0; d < 8; ++d) ab[d] = (short)f2bf(ov[d]);
    *(s16x8*)(agg_b + gtok * 512 + c0) = ab;
  }
}

// ---------------------------------------------------------------- K3: ffn1 + gelu
// flat grid 2048, XCD swizzle groups the 16 col-tiles of one row-tile per XCD.
__launch_bounds__(256)
__global__ void ffn1_kernel(const unsigned short* __restrict__ aggb,
                            const unsigned short* __restrict__ w1b,
                            const float* __restrict__ b1,
                            unsigned short* __restrict__ hidden) {
  const int wg = blockIdx.x;
  const int slot = wg >> 3, xcd = wg & 7;
  const int by = ((slot >> 4) << 3) | xcd;  // [0,128) row-tile
  const int bx = slot & 15;                 // [0,16)  col-tile
  const int tid = threadIdx.x, lane = tid & 63, w = tid >> 6;
  const int wm = w >> 1, wn = w & 1;
  __shared__ __align__(16) unsigned char smem[32768];
  unsigned short* aT = (unsigned short*)smem;            // [128][64]
  unsigned short* bT = (unsigned short*)(smem + 16384);  // [128][64]
  f32x4 acc[4][4];
#pragma unroll
  for (int i = 0; i < 4; ++i)
#pragma unroll
    for (int j = 0; j < 4; ++j) acc[i][j] = (f32x4){0.f, 0.f, 0.f, 0.f};
  const long rowBase = (long)by * 128;
  const long colBase = (long)bx * 128;
  for (int kk = 0; kk < 8; ++kk) {
    const int k0 = kk * 64;
#pragma unroll
    for (int it = 0; it < 4; ++it) {
      int cid = tid + it * 256, lr = cid >> 3, c8 = cid & 7;
      s16x8 v = *(const s16x8*)(aggb + (rowBase + lr) * 512 + k0 + c8 * 8);
      *(s16x8*)((unsigned char*)aT + swz(lr, c8 * 16)) = v;
    }
#pragma unroll
    for (int it = 0; it < 4; ++it) {
      int cid = tid + it * 256, bc = cid >> 3, c8 = cid & 7;
      s16x8 v = *(const s16x8*)(w1b + (colBase + bc) * 512 + k0 + c8 * 8);
      *(s16x8*)((unsigned char*)bT + swz(bc, c8 * 16)) = v;
    }
    __syncthreads();
#pragma unroll
    for (int k2 = 0; k2 < 2; ++k2) {
      s16x8 af[4], bfr[4];
      const int bir = k2 * 64 + ((lane >> 4) << 4);
#pragma unroll
      for (int mi = 0; mi < 4; ++mi) {
        int row = wm * 64 + mi * 16 + (lane & 15);
        af[mi] = *(const s16x8*)((unsigned char*)aT + swz(row, bir));
      }
#pragma unroll
      for (int ni = 0; ni < 4; ++ni) {
        int col = wn * 64 + ni * 16 + (lane & 15);
        bfr[ni] = *(const s16x8*)((unsigned char*)bT + swz(col, bir));
      }
#pragma unroll
      for (int mi = 0; mi < 4; ++mi)
#pragma unroll
        for (int ni = 0; ni < 4; ++ni)
          acc[mi][ni] = mfma16(af[mi], bfr[ni], acc[mi][ni]);
    }
    __syncthreads();
  }
#pragma unroll
  for (int mi = 0; mi < 4; ++mi)
#pragma unroll
    for (int ni = 0; ni < 4; ++ni) {
      long gcol = colBase + wn * 64 + ni * 16 + (lane & 15);
      float bias = b1[gcol];
      int row0 = wm * 64 + mi * 16 + ((lane >> 4) << 2);
#pragma unroll
      for (int r = 0; r < 4; ++r) {
        float x = acc[mi][ni][r] + bias;
        float g = 0.5f * x * (1.f + erff(x * 0.70710678118f));
        hidden[(rowBase + row0 + r) * 2048 + gcol] = f2bf(g);
      }
    }
}

// ---------------------------------------------------------------- K4: ffn2 + LN2
// grid 512 (32 tokens each), 256 threads. agg residual folded into vt.
__launch_bounds__(256)
__global__ void ffn2_ln2_kernel(const unsigned short* __restrict__ hidden,
                                const unsigned short* __restrict__ w2b,
                                const float* __restrict__ b2,
                                const float* __restrict__ agg_f,
                                const float* __restrict__ ln2_g,
                                const float* __restrict__ ln2_b,
                                float* __restrict__ out) {
  const int tb = blockIdx.x;
  const int tid = threadIdx.x, lane = tid & 63, w = tid >> 6;
  __shared__ __align__(16) unsigned char smem[53504];
  unsigned short* vt = (unsigned short*)smem;            // [32][512], XOR-swizzled
  unsigned short* aT = (unsigned short*)(smem + 32768);  // [32][64]
  unsigned short* bT = (unsigned short*)(smem + 36864);  // [128][64]
  float* stats = (float*)(smem + 53248);
  const long rowBase = (long)tb * 32;  // token rows

  for (int ns = 0; ns < 4; ++ns) {
    f32x4 acc[2][2];
#pragma unroll
    for (int i = 0; i < 2; ++i)
#pragma unroll
      for (int j = 0; j < 2; ++j) acc[i][j] = (f32x4){0.f, 0.f, 0.f, 0.f};
    for (int kk = 0; kk < 32; ++kk) {
      const int k0 = kk * 64;
      {
        int lr = tid >> 3, c8 = tid & 7;
        s16x8 v = *(const s16x8*)(hidden + (rowBase + lr) * 2048 + k0 + c8 * 8);
        *(s16x8*)((unsigned char*)aT + swz(lr, c8 * 16)) = v;
      }
#pragma unroll
      for (int it = 0; it < 4; ++it) {
        int cid = tid + it * 256, bc = cid >> 3, c8 = cid & 7;
        s16x8 v = *(const s16x8*)(w2b + (long)(ns * 128 + bc) * 2048 + k0 + c8 * 8);
        *(s16x8*)((unsigned char*)bT + swz(bc, c8 * 16)) = v;
      }
      __syncthreads();
#pragma unroll
      for (int k2 = 0; k2 < 2; ++k2) {
        s16x8 af[2], bfr[2];
        const int bir = k2 * 64 + ((lane >> 4) << 4);
#pragma unroll
        for (int mi = 0; mi < 2; ++mi) {
          int row = mi * 16 + (lane & 15);
          af[mi] = *(const s16x8*)((unsigned char*)aT + swz(row, bir));
        }
#pragma unroll
        for (int ni = 0; ni < 2; ++ni) {
          int col = w * 32 + ni * 16 + (lane & 15);
          bfr[ni] = *(const s16x8*)((unsigned char*)bT + swz(col, bir));
        }
#pragma unroll
        for (int mi = 0; mi < 2; ++mi)
#pragma unroll
          for (int ni = 0; ni < 2; ++ni)
            acc[mi][ni] = mfma16(af[mi], bfr[ni], acc[mi][ni]);
      }
      __syncthreads();
    }
#pragma unroll
    for (int mi = 0; mi < 2; ++mi)
#pragma unroll
      for (int ni = 0; ni < 2; ++ni) {
        int gcol = ns * 128 + w * 32 + ni * 16 + (lane & 15);
        float bias = b2[gcol];
        int row0 = mi * 16 + ((lane >> 4) << 2);
#pragma unroll
        for (int r = 0; r < 4; ++r) {
          int rr = row0 + r;
          float ag = agg_f[(rowBase + rr) * 512 + gcol];
          *(unsigned short*)((unsigned char*)vt + vtoff(rr, gcol)) =
              f2bf(acc[mi][ni][r] + bias + ag);
        }
      }
  }
  __syncthreads();
  {  // LN2 stats: one wave per 8 rows
    int wv = tid >> 6, ln = tid & 63;
    for (int i = 0; i < 8; ++i) {
      int r = wv * 8 + i;
      s16x8 v8 = *(const s16x8*)((unsigned char*)vt + vtoff(r, ln * 8));
      float sum = 0.f, sq = 0.f;
#pragma unroll
      for (int d = 0; d < 8; ++d) {
        float v = bf2f((unsigned short)v8[d]);
        sum += v; sq += v * v;
      }
#pragma unroll
      for (int off = 1; off < 64; off <<= 1) {
        sum += __shfl_xor(sum, off); sq += __shfl_xor(sq, off);
      }
      if (ln == 0) {
        float mu = sum * (1.f / 512.f);
        float var = sq * (1.f / 512.f) - mu * mu;
        stats[r * 2] = mu;
        stats[r * 2 + 1] = rsqrtf(var + 1e-5f);
      }
    }
  }
  __syncthreads();
  for (int it = 0; it < 8; ++it) {
    int ci = tid + it * 256;
    int r = ci >> 6, c0 = (ci & 63) * 8;
    s16x8 v8 = *(const s16x8*)((unsigned char*)vt + vtoff(r, c0));
    float mu = stats[r * 2], is = stats[r * 2 + 1];
    float4 g0 = *(const float4*)(ln2_g + c0);
    float4 g1 = *(const float4*)(ln2_g + c0 + 4);
    float4 b0 = *(const float4*)(ln2_b + c0);
    float4 b1 = *(const float4*)(ln2_b + c0 + 4);
    float vv[8];
#pragma unroll
    for (int d = 0; d < 8; ++d) vv[d] = (bf2f((unsigned short)v8[d]) - mu) * is;
    float* dst = out + (rowBase + r) * 512 + c0;
    *(float4*)dst = (float4){vv[0] * g0.x + b0.x, vv[1] * g0.y + b0.y,
                             vv[2] * g0.z + b0.z, vv[3] * g0.w + b0.w};
    *(float4*)(dst + 4) = (float4){vv[4] * g1.x + b1.x, vv[5] * g1.y + b1.y,
                                   vv[6] * g1.z + b1.z, vv[7] * g1.w + b1.w};
  }
}

// ---------------------------------------------------------------- launch
extern "C" void kernel_launch(void* const* d_in, const int* in_sizes, int n_in,
                              void* d_out, int out_size, void* d_ws, size_t ws_size,
                              hipStream_t stream) {
  (void)in_sizes; (void)n_in; (void)out_size;
  const float* x0 = (const float*)d_in[0];
  const float* x1 = (const float*)d_in[1];
  const float* x2 = (const float*)d_in[2];
  const float* x3 = (const float*)d_in[3];
  const float* in_w = (const float*)d_in[4];
  const float* in_b = (const float*)d_in[5];
  const float* out_w = (const float*)d_in[6];
  const float* out_b = (const float*)d_in[7];
  const float* ln1_g = (const float*)d_in[8];
  const float* ln1_b = (const float*)d_in[9];
  const float* w1 = (const float*)d_in[10];
  const float* b1 = (const float*)d_in[11];
  const float* w2 = (const float*)d_in[12];
  const float* b2 = (const float*)d_in[13];
  const float* ln2_g = (const float*)d_in[14];
  const float* ln2_b = (const float*)d_in[15];
  float* out = (float*)d_out;

  unsigned char* ws = (unsigned char*)d_ws;
  if (ws_size < 190840832u) return;
  unsigned short* wqkv_b = (unsigned short*)(ws + 0);
  unsigned short* wout_b = (unsigned short*)(ws + 1572864);
  unsigned short* w1_b = (unsigned short*)(ws + 2097152);
  unsigned short* w2_b = (unsigned short*)(ws + 4194304);
  unsigned short* x4 = (unsigned short*)(ws + 6291456);
  unsigned short* o_buf = (unsigned short*)(ws + 73400320);
  float* agg_f = (float*)(ws + 140509184);
  unsigned short* agg_b = (unsigned short*)(ws + 174063616);
  unsigned short* hidden = o_buf;  // overlay: o dead after K2

  pack_kernel<<<2048, 256, 0, stream>>>(in_w, out_w, w1, w2, x0, x1, x2, x3,
                                        wqkv_b, wout_b, w1_b, w2_b, x4);
  qkv_attn_kernel<<<4096, 256, 0, stream>>>(x4, wqkv_b, in_b, o_buf);
  outproj_ln1_kernel<<<2048, 256, 0, stream>>>(o_buf, wout_b, out_b, x0, x1, x2, x3,
                                               ln1_g, ln1_b, agg_f, agg_b);
  ffn1_kernel<<<2048, 256, 0, stream>>>(agg_b, w1_b, b1, hidden);
  ffn2_ln2_kernel<<<512, 256, 0, stream>>>(hidden, w2_b, b2, agg_f, ln2_g, ln2_b, out);
}